// Round 3
// baseline (58.528 us; speedup 1.0000x reference)
//
#include <hip/hip_runtime.h>
#include <math.h>

// Problem constants (from reference)
constexpr int NFILT = 128;
constexpr int FILTER_SIZE = 1025;
constexpr int HALF = 2;            // (2048/2+1)//128//4
constexpr int F_DIM = 1025;        // NFFT//2+1
constexpr int B_DIM = 32;
constexpr int T_DIM = 3000;

constexpr int NCHUNK = 16;              // n-chunks per batch
constexpr int NPC = NFILT / NCHUNK;     // 8 filters per block
constexpr int MAXW = 8;                 // precomputed taps per filter

typedef float f32x4 __attribute__((ext_vector_type(4)));

// ---------------------------------------------------------------------------
// Single fused kernel. Every block redoes the (tiny) setup from LDS:
//   - cooperative load of w (1 KB) into LDS
//   - thread 0: serial f32 cumsum of clipped cn (exact np.cumsum order)
//   - thread 64 (block 0 only): scalar loss -> d_out tail
//   - threads 0..7: band bounds; threads 0..63: Gaussian taps
// Then the banded reduction: res[b,n,t] = sum_f g(n,f) * in[b,f,t],
// float4 along t, non-temporal output stores.
// ---------------------------------------------------------------------------
__global__ __launch_bounds__(256) void gauss_fused(
    const float* __restrict__ w,
    const float* __restrict__ in,
    float* __restrict__ out,
    float* __restrict__ loss_out) {
    __shared__ float cn_sh[NFILT], sg_sh[NFILT], c_sh[NFILT];
    __shared__ float cc_sh[NPC], rsg_sh[NPC];
    __shared__ int lo_sh[NPC], wd_sh[NPC];
    __shared__ float wt_sh[NPC][MAXW];

    const int tid = threadIdx.x;
    const int chunk = blockIdx.y;   // 0..NCHUNK-1
    const int b = blockIdx.z;       // 0..31
    const int n0 = chunk * NPC;

    // cooperative load of w into LDS
    if (tid < NFILT) cn_sh[tid] = w[2 * tid];
    else             sg_sh[tid - NFILT] = w[2 * (tid - NFILT) + 1];
    __syncthreads();

    if (tid == 0) {
        // serial f32 cumsum of clipped cn (matches np.cumsum sequential order)
        float c = 0.0f;
        for (int i = 0; i < NFILT; ++i) {
            float cnc = cn_sh[i];
            if (cnc < 30.0f / 80000.0f) cnc = 30.0f / 80000.0f;
            if (cnc > 1.0f) cnc = 1.0f;
            c += cnc;
            c_sh[i] = c;
        }
    }
    // loss: one block, separate wave so it overlaps the cumsum chain
    if (tid == 64 && blockIdx.x == 0 && chunk == 0 && b == 0) {
        float s_cn = 0.0f, pl = 0.0f;
        for (int i = 0; i < NFILT; ++i) {
            float cn = cn_sh[i];
            float sg = sg_sh[i];
            s_cn += cn;
            if (cn < 0.0f) pl += -cn;
            if (sg < 0.0f) pl += -sg;
        }
        float loss = pl * 1000.0f;
        float pdc;
        if (s_cn >= 0.2f && s_cn <= 0.5f) pdc = 0.0f;
        else pdc = (s_cn < 0.2f ? expf(-s_cn) : expf(s_cn)) * 100.0f;
        loss_out[0] = loss + pdc;
    }
    __syncthreads();

    // band bounds for this block's 8 filters
    if (tid < NPC) {
        const int n = n0 + tid;
        const float c = c_sh[n];
        float sg = sg_sh[n];
        if (sg < 0.0001f) sg = 0.0001f;
        if (sg > 0.05f) sg = 0.05f;
        int ic = (int)floorf(c * (float)FILTER_SIZE);
        int lo = ic - HALF;
        int blo = (lo >= 0 && lo < FILTER_SIZE) ? lo : 0;
        int hi = ic + HALF;
        int bhi = (hi < FILTER_SIZE) ? (hi + 1) : (FILTER_SIZE - 1);
        int wd = bhi - blo;
        if (wd < 0) wd = 0;
        cc_sh[tid] = c;
        rsg_sh[tid] = 1.0f / sg;
        lo_sh[tid] = blo;
        wd_sh[tid] = wd;
    }
    __syncthreads();

    // taps: 64 threads, one (filter, tap) each — exact ref arithmetic
    if (tid < NPC * MAXW) {
        const int ni = tid / MAXW, j = tid % MAXW;
        float g = 0.0f;
        if (j < wd_sh[ni]) {
            const int n = n0 + ni;
            float sg = sg_sh[n];
            if (sg < 0.0001f) sg = 0.0001f;
            if (sg > 0.05f) sg = 0.05f;
            float tv = (float)(lo_sh[ni] + j) / (float)FILTER_SIZE;
            float z = (tv - cc_sh[ni]) / sg;
            g = expf(-0.5f * z * z);
        }
        wt_sh[ni][j] = g;
    }
    __syncthreads();

    const int t0 = blockIdx.x * 1024 + tid * 4;
    if (t0 >= T_DIM) return;

    const float* inb = in + (size_t)b * F_DIM * T_DIM;
    float* outb = out + ((size_t)b * NFILT + (size_t)n0) * T_DIM;

    for (int ni = 0; ni < NPC; ++ni) {
        const int lo = lo_sh[ni];
        const int wd = wd_sh[ni];
        const float* src = inb + (size_t)lo * T_DIM + t0;

        float ax = 0.0f, ay = 0.0f, az = 0.0f, aw = 0.0f;
        if (wd == 5) {
            // common case: fully unrolled, 5 independent loads + FMAs
            #pragma unroll
            for (int j = 0; j < 5; ++j) {
                const float g = wt_sh[ni][j];
                const f32x4 v = *reinterpret_cast<const f32x4*>(src + (size_t)j * T_DIM);
                ax += g * v.x; ay += g * v.y; az += g * v.z; aw += g * v.w;
            }
        } else if (wd <= MAXW) {
            for (int j = 0; j < wd; ++j) {
                const float g = wt_sh[ni][j];
                const f32x4 v = *reinterpret_cast<const f32x4*>(src + (size_t)j * T_DIM);
                ax += g * v.x; ay += g * v.y; az += g * v.z; aw += g * v.w;
            }
        } else {
            // rare wide-band clamp case: compute g inline
            const float c = cc_sh[ni];
            const float rsg = rsg_sh[ni];
            for (int j = 0; j < wd; ++j) {
                float tv = (float)(lo + j) / (float)FILTER_SIZE;
                float z = (tv - c) * rsg;
                float g = expf(-0.5f * z * z);
                const f32x4 v = *reinterpret_cast<const f32x4*>(src + (size_t)j * T_DIM);
                ax += g * v.x; ay += g * v.y; az += g * v.z; aw += g * v.w;
            }
        }
        f32x4 r;
        r.x = ax; r.y = ay; r.z = az; r.w = aw;
        __builtin_nontemporal_store(
            r, reinterpret_cast<f32x4*>(outb + (size_t)ni * T_DIM + t0));
    }
}

extern "C" void kernel_launch(void* const* d_in, const int* in_sizes, int n_in,
                              void* d_out, int out_size, void* d_ws, size_t ws_size,
                              hipStream_t stream) {
    const float* inputs = (const float*)d_in[0];  // (32, 1025, 3000) f32
    const float* w = (const float*)d_in[1];       // (128, 2) f32

    float* out = (float*)d_out;                   // res (32,128,3000) then loss
    float* loss_out = out + (size_t)B_DIM * NFILT * T_DIM;

    dim3 grid((T_DIM + 1023) / 1024, NCHUNK, B_DIM);  // (3, 16, 32)
    gauss_fused<<<grid, 256, 0, stream>>>(w, inputs, out, loss_out);
}

// Round 4
// 55.590 us; speedup vs baseline: 1.0528x; 1.0528x over previous
//
#include <hip/hip_runtime.h>
#include <math.h>

// Problem constants (from reference)
constexpr int NFILT = 128;
constexpr int FILTER_SIZE = 1025;
constexpr int HALF = 2;            // (2048/2+1)//128//4
constexpr int F_DIM = 1025;        // NFFT//2+1
constexpr int B_DIM = 32;
constexpr int T_DIM = 3000;

constexpr int NCHUNK = 32;              // n-chunks per batch
constexpr int NPC = NFILT / NCHUNK;     // 4 filters per block
constexpr int MAXW = 8;                 // precomputed taps per filter
constexpr int NF4 = T_DIM / 4;          // 750 float4 per row

typedef float f32x4 __attribute__((ext_vector_type(4)));

// ---------------------------------------------------------------------------
// Kernel 1: cumsum, bands, loss, and precomputed Gaussian tap weights.
// ---------------------------------------------------------------------------
__global__ __launch_bounds__(128) void gauss_setup(
    const float* __restrict__ w,
    float* __restrict__ c_out,
    float* __restrict__ rsg_out,
    int* __restrict__ lo_out,
    int* __restrict__ wd_out,
    float* __restrict__ wt_out,
    float* __restrict__ loss_out) {
    __shared__ float cn_sh[NFILT];
    __shared__ float sg_sh[NFILT];
    __shared__ float c_sh[NFILT];
    const int tid = threadIdx.x;

    // cooperative load of w into LDS (coalesced: 256 consecutive floats)
    cn_sh[tid] = w[2 * tid];
    sg_sh[tid] = w[2 * tid + 1];
    __syncthreads();

    if (tid == 0) {
        // serial f32 cumsum of clipped cn (matches np.cumsum order), from LDS
        float c = 0.0f;
        float s_cn = 0.0f, pl_cn = 0.0f, pl_sig = 0.0f;
        for (int i = 0; i < NFILT; ++i) {
            float cn = cn_sh[i];
            float sg = sg_sh[i];
            s_cn += cn;
            if (cn < 0.0f) pl_cn += -cn;
            if (sg < 0.0f) pl_sig += -sg;
            float cnc = cn;
            if (cnc < 30.0f / 80000.0f) cnc = 30.0f / 80000.0f;
            if (cnc > 1.0f) cnc = 1.0f;
            c += cnc;
            c_sh[i] = c;
        }
        float loss = (pl_cn + pl_sig) * 1000.0f;
        float pdc;
        if (s_cn >= 0.2f && s_cn <= 0.5f) pdc = 0.0f;
        else pdc = (s_cn < 0.2f ? expf(-s_cn) : expf(s_cn)) * 100.0f;
        loss_out[0] = loss + pdc;
    }
    __syncthreads();

    // per-filter band + weights
    float sg = sg_sh[tid];
    if (sg < 0.0001f) sg = 0.0001f;
    if (sg > 0.05f) sg = 0.05f;
    const float c = c_sh[tid];

    int ic = (int)floorf(c * (float)FILTER_SIZE);
    int lo = ic - HALF;
    int blo = (lo >= 0 && lo < FILTER_SIZE) ? lo : 0;
    int hi = ic + HALF;
    int bhi = (hi < FILTER_SIZE) ? (hi + 1) : (FILTER_SIZE - 1);
    int wd = bhi - blo;              // may be <=0 (empty) or huge (wide clamp)
    if (wd < 0) wd = 0;

    c_out[tid] = c;
    rsg_out[tid] = 1.0f / sg;
    lo_out[tid] = blo;
    wd_out[tid] = wd;

    // precompute up to MAXW taps (exact ref arithmetic: f32 div + expf)
    for (int j = 0; j < MAXW; ++j) {
        float g = 0.0f;
        if (j < wd) {
            float tv = (float)(blo + j) / (float)FILTER_SIZE;
            float z = (tv - c) / sg;
            g = expf(-0.5f * z * z);
        }
        wt_out[tid * MAXW + j] = g;
    }
}

// ---------------------------------------------------------------------------
// Kernel 2: banded reduction with precomputed weights.
// Each thread owns THREE float4 t-positions (tid, tid+256, min(tid+512,749)),
// so a wd=5 filter has 15 independent loads in flight (240 B/thread).
// Grid: (1, 32, 32) -> 1024 blocks, 4 filters per block, NT output stores.
// ---------------------------------------------------------------------------
__global__ __launch_bounds__(256) void gauss_apply(
    const float* __restrict__ in,
    const float* __restrict__ cArr,
    const float* __restrict__ rsgArr,
    const int* __restrict__ loArr,
    const int* __restrict__ wdArr,
    const float* __restrict__ wtArr,
    float* __restrict__ out) {
    __shared__ float c_sh[NPC], rsg_sh[NPC];
    __shared__ int lo_sh[NPC], wd_sh[NPC];
    __shared__ float wt_sh[NPC][MAXW];

    const int tid = threadIdx.x;
    const int chunk = blockIdx.y;   // 0..NCHUNK-1
    const int b = blockIdx.z;       // 0..31
    const int n0 = chunk * NPC;

    if (tid < NPC) {
        c_sh[tid] = cArr[n0 + tid];
        rsg_sh[tid] = rsgArr[n0 + tid];
        lo_sh[tid] = loArr[n0 + tid];
        wd_sh[tid] = wdArr[n0 + tid];
    }
    if (tid < NPC * MAXW) {
        wt_sh[tid / MAXW][tid % MAXW] = wtArr[n0 * MAXW + tid];
    }
    __syncthreads();

    // three float4 column positions per thread (stride-256 => coalesced waves)
    const int f40 = tid;                       // < 750 always
    const int f41 = tid + 256;                 // < 750 always
    const bool ok2 = (tid + 512) < NF4;        // tid < 238
    const int f42 = ok2 ? (tid + 512) : (NF4 - 1);  // clamp: dup load, no store

    const float* inb = in + (size_t)b * F_DIM * T_DIM;
    float* outb = out + ((size_t)b * NFILT + (size_t)n0) * T_DIM;

    for (int ni = 0; ni < NPC; ++ni) {
        const int lo = lo_sh[ni];
        const int wd = wd_sh[ni];
        const float* src = inb + (size_t)lo * T_DIM;

        f32x4 a0 = {0.f, 0.f, 0.f, 0.f};
        f32x4 a1 = {0.f, 0.f, 0.f, 0.f};
        f32x4 a2 = {0.f, 0.f, 0.f, 0.f};

        if (wd == 5) {
            // common case: 15 independent loads, fully unrolled
            #pragma unroll
            for (int r = 0; r < 5; ++r) {
                const float g = wt_sh[ni][r];
                const float* row = src + (size_t)r * T_DIM;
                const f32x4 v0 = *reinterpret_cast<const f32x4*>(row + 4 * (size_t)f40);
                const f32x4 v1 = *reinterpret_cast<const f32x4*>(row + 4 * (size_t)f41);
                const f32x4 v2 = *reinterpret_cast<const f32x4*>(row + 4 * (size_t)f42);
                a0 += g * v0; a1 += g * v1; a2 += g * v2;
            }
        } else if (wd <= MAXW) {
            for (int r = 0; r < wd; ++r) {
                const float g = wt_sh[ni][r];
                const float* row = src + (size_t)r * T_DIM;
                const f32x4 v0 = *reinterpret_cast<const f32x4*>(row + 4 * (size_t)f40);
                const f32x4 v1 = *reinterpret_cast<const f32x4*>(row + 4 * (size_t)f41);
                const f32x4 v2 = *reinterpret_cast<const f32x4*>(row + 4 * (size_t)f42);
                a0 += g * v0; a1 += g * v1; a2 += g * v2;
            }
        } else {
            // rare wide-band clamp case: compute g inline
            const float c = c_sh[ni];
            const float rsg = rsg_sh[ni];
            for (int r = 0; r < wd; ++r) {
                float tv = (float)(lo + r) / (float)FILTER_SIZE;
                float z = (tv - c) * rsg;
                float g = expf(-0.5f * z * z);
                const float* row = src + (size_t)r * T_DIM;
                const f32x4 v0 = *reinterpret_cast<const f32x4*>(row + 4 * (size_t)f40);
                const f32x4 v1 = *reinterpret_cast<const f32x4*>(row + 4 * (size_t)f41);
                const f32x4 v2 = *reinterpret_cast<const f32x4*>(row + 4 * (size_t)f42);
                a0 += g * v0; a1 += g * v1; a2 += g * v2;
            }
        }

        float* orow = outb + (size_t)ni * T_DIM;
        __builtin_nontemporal_store(a0, reinterpret_cast<f32x4*>(orow + 4 * (size_t)f40));
        __builtin_nontemporal_store(a1, reinterpret_cast<f32x4*>(orow + 4 * (size_t)f41));
        if (ok2) {
            __builtin_nontemporal_store(a2, reinterpret_cast<f32x4*>(orow + 4 * (size_t)f42));
        }
    }
}

extern "C" void kernel_launch(void* const* d_in, const int* in_sizes, int n_in,
                              void* d_out, int out_size, void* d_ws, size_t ws_size,
                              hipStream_t stream) {
    const float* inputs = (const float*)d_in[0];  // (32, 1025, 3000) f32
    const float* w = (const float*)d_in[1];       // (128, 2) f32

    float* out = (float*)d_out;                   // res (32,128,3000) then loss
    float* loss_out = out + (size_t)B_DIM * NFILT * T_DIM;

    float* c_arr = (float*)d_ws;
    float* rsg_arr = c_arr + NFILT;
    int* lo_arr = (int*)(rsg_arr + NFILT);
    int* wd_arr = lo_arr + NFILT;
    float* wt_arr = (float*)(wd_arr + NFILT);

    gauss_setup<<<1, 128, 0, stream>>>(w, c_arr, rsg_arr, lo_arr, wd_arr,
                                       wt_arr, loss_out);

    dim3 grid(1, NCHUNK, B_DIM);  // (1, 32, 32)
    gauss_apply<<<grid, 256, 0, stream>>>(inputs, c_arr, rsg_arr, lo_arr,
                                          wd_arr, wt_arr, out);
}

// Round 5
// 55.239 us; speedup vs baseline: 1.0595x; 1.0064x over previous
//
#include <hip/hip_runtime.h>
#include <math.h>

// Problem constants (from reference)
constexpr int NFILT = 128;
constexpr int FILTER_SIZE = 1025;
constexpr int HALF = 2;            // (2048/2+1)//128//4
constexpr int F_DIM = 1025;        // NFFT//2+1
constexpr int B_DIM = 32;
constexpr int T_DIM = 3000;

constexpr int NCHUNK = 64;              // n-chunks per batch
constexpr int NPC = NFILT / NCHUNK;     // 2 filters per block
constexpr int MAXW = 8;                 // precomputed taps per filter
constexpr int NF4 = T_DIM / 4;          // 750 float4 per row

typedef float f32x4 __attribute__((ext_vector_type(4)));

// ---------------------------------------------------------------------------
// Kernel 1: cumsum, bands, loss, and precomputed Gaussian tap weights.
// ---------------------------------------------------------------------------
__global__ __launch_bounds__(128) void gauss_setup(
    const float* __restrict__ w,
    float* __restrict__ c_out,
    float* __restrict__ rsg_out,
    int* __restrict__ lo_out,
    int* __restrict__ wd_out,
    float* __restrict__ wt_out,
    float* __restrict__ loss_out) {
    __shared__ float cn_sh[NFILT];
    __shared__ float sg_sh[NFILT];
    __shared__ float c_sh[NFILT];
    const int tid = threadIdx.x;

    // cooperative load of w into LDS (coalesced: 256 consecutive floats)
    cn_sh[tid] = w[2 * tid];
    sg_sh[tid] = w[2 * tid + 1];
    __syncthreads();

    if (tid == 0) {
        // serial f32 cumsum of clipped cn (matches np.cumsum order), from LDS
        float c = 0.0f;
        float s_cn = 0.0f, pl_cn = 0.0f, pl_sig = 0.0f;
        for (int i = 0; i < NFILT; ++i) {
            float cn = cn_sh[i];
            float sg = sg_sh[i];
            s_cn += cn;
            if (cn < 0.0f) pl_cn += -cn;
            if (sg < 0.0f) pl_sig += -sg;
            float cnc = cn;
            if (cnc < 30.0f / 80000.0f) cnc = 30.0f / 80000.0f;
            if (cnc > 1.0f) cnc = 1.0f;
            c += cnc;
            c_sh[i] = c;
        }
        float loss = (pl_cn + pl_sig) * 1000.0f;
        float pdc;
        if (s_cn >= 0.2f && s_cn <= 0.5f) pdc = 0.0f;
        else pdc = (s_cn < 0.2f ? expf(-s_cn) : expf(s_cn)) * 100.0f;
        loss_out[0] = loss + pdc;
    }
    __syncthreads();

    // per-filter band + weights
    float sg = sg_sh[tid];
    if (sg < 0.0001f) sg = 0.0001f;
    if (sg > 0.05f) sg = 0.05f;
    const float c = c_sh[tid];

    int ic = (int)floorf(c * (float)FILTER_SIZE);
    int lo = ic - HALF;
    int blo = (lo >= 0 && lo < FILTER_SIZE) ? lo : 0;
    int hi = ic + HALF;
    int bhi = (hi < FILTER_SIZE) ? (hi + 1) : (FILTER_SIZE - 1);
    int wd = bhi - blo;              // may be <=0 (empty) or huge (wide clamp)
    if (wd < 0) wd = 0;

    c_out[tid] = c;
    rsg_out[tid] = 1.0f / sg;
    lo_out[tid] = blo;
    wd_out[tid] = wd;

    // precompute up to MAXW taps (exact ref arithmetic: f32 div + expf)
    for (int j = 0; j < MAXW; ++j) {
        float g = 0.0f;
        if (j < wd) {
            float tv = (float)(blo + j) / (float)FILTER_SIZE;
            float z = (tv - c) / sg;
            g = expf(-0.5f * z * z);
        }
        wt_out[tid * MAXW + j] = g;
    }
}

// ---------------------------------------------------------------------------
// Kernel 2: banded reduction with precomputed weights.
// Each thread owns THREE float4 t-positions (tid, tid+256, min(tid+512,749)),
// so a wd=5 filter has 15 independent loads in flight (240 B/thread).
// Grid: (1, 64, 32) -> 2048 blocks = 32 waves/CU (full occupancy),
// 2 filters per block, NT output stores.
// ---------------------------------------------------------------------------
__global__ __launch_bounds__(256) void gauss_apply(
    const float* __restrict__ in,
    const float* __restrict__ cArr,
    const float* __restrict__ rsgArr,
    const int* __restrict__ loArr,
    const int* __restrict__ wdArr,
    const float* __restrict__ wtArr,
    float* __restrict__ out) {
    __shared__ float c_sh[NPC], rsg_sh[NPC];
    __shared__ int lo_sh[NPC], wd_sh[NPC];
    __shared__ float wt_sh[NPC][MAXW];

    const int tid = threadIdx.x;
    const int chunk = blockIdx.y;   // 0..NCHUNK-1
    const int b = blockIdx.z;       // 0..31
    const int n0 = chunk * NPC;

    if (tid < NPC) {
        c_sh[tid] = cArr[n0 + tid];
        rsg_sh[tid] = rsgArr[n0 + tid];
        lo_sh[tid] = loArr[n0 + tid];
        wd_sh[tid] = wdArr[n0 + tid];
    }
    if (tid < NPC * MAXW) {
        wt_sh[tid / MAXW][tid % MAXW] = wtArr[n0 * MAXW + tid];
    }
    __syncthreads();

    // three float4 column positions per thread (stride-256 => coalesced waves)
    const int f40 = tid;                       // < 750 always
    const int f41 = tid + 256;                 // < 750 always
    const bool ok2 = (tid + 512) < NF4;        // tid < 238
    const int f42 = ok2 ? (tid + 512) : (NF4 - 1);  // clamp: dup load, no store

    const float* inb = in + (size_t)b * F_DIM * T_DIM;
    float* outb = out + ((size_t)b * NFILT + (size_t)n0) * T_DIM;

    for (int ni = 0; ni < NPC; ++ni) {
        const int lo = lo_sh[ni];
        const int wd = wd_sh[ni];
        const float* src = inb + (size_t)lo * T_DIM;

        f32x4 a0 = {0.f, 0.f, 0.f, 0.f};
        f32x4 a1 = {0.f, 0.f, 0.f, 0.f};
        f32x4 a2 = {0.f, 0.f, 0.f, 0.f};

        if (wd == 5) {
            // common case: 15 independent loads, fully unrolled
            #pragma unroll
            for (int r = 0; r < 5; ++r) {
                const float g = wt_sh[ni][r];
                const float* row = src + (size_t)r * T_DIM;
                const f32x4 v0 = *reinterpret_cast<const f32x4*>(row + 4 * (size_t)f40);
                const f32x4 v1 = *reinterpret_cast<const f32x4*>(row + 4 * (size_t)f41);
                const f32x4 v2 = *reinterpret_cast<const f32x4*>(row + 4 * (size_t)f42);
                a0 += g * v0; a1 += g * v1; a2 += g * v2;
            }
        } else if (wd <= MAXW) {
            for (int r = 0; r < wd; ++r) {
                const float g = wt_sh[ni][r];
                const float* row = src + (size_t)r * T_DIM;
                const f32x4 v0 = *reinterpret_cast<const f32x4*>(row + 4 * (size_t)f40);
                const f32x4 v1 = *reinterpret_cast<const f32x4*>(row + 4 * (size_t)f41);
                const f32x4 v2 = *reinterpret_cast<const f32x4*>(row + 4 * (size_t)f42);
                a0 += g * v0; a1 += g * v1; a2 += g * v2;
            }
        } else {
            // rare wide-band clamp case: compute g inline
            const float c = c_sh[ni];
            const float rsg = rsg_sh[ni];
            for (int r = 0; r < wd; ++r) {
                float tv = (float)(lo + r) / (float)FILTER_SIZE;
                float z = (tv - c) * rsg;
                float g = expf(-0.5f * z * z);
                const float* row = src + (size_t)r * T_DIM;
                const f32x4 v0 = *reinterpret_cast<const f32x4*>(row + 4 * (size_t)f40);
                const f32x4 v1 = *reinterpret_cast<const f32x4*>(row + 4 * (size_t)f41);
                const f32x4 v2 = *reinterpret_cast<const f32x4*>(row + 4 * (size_t)f42);
                a0 += g * v0; a1 += g * v1; a2 += g * v2;
            }
        }

        float* orow = outb + (size_t)ni * T_DIM;
        __builtin_nontemporal_store(a0, reinterpret_cast<f32x4*>(orow + 4 * (size_t)f40));
        __builtin_nontemporal_store(a1, reinterpret_cast<f32x4*>(orow + 4 * (size_t)f41));
        if (ok2) {
            __builtin_nontemporal_store(a2, reinterpret_cast<f32x4*>(orow + 4 * (size_t)f42));
        }
    }
}

extern "C" void kernel_launch(void* const* d_in, const int* in_sizes, int n_in,
                              void* d_out, int out_size, void* d_ws, size_t ws_size,
                              hipStream_t stream) {
    const float* inputs = (const float*)d_in[0];  // (32, 1025, 3000) f32
    const float* w = (const float*)d_in[1];       // (128, 2) f32

    float* out = (float*)d_out;                   // res (32,128,3000) then loss
    float* loss_out = out + (size_t)B_DIM * NFILT * T_DIM;

    float* c_arr = (float*)d_ws;
    float* rsg_arr = c_arr + NFILT;
    int* lo_arr = (int*)(rsg_arr + NFILT);
    int* wd_arr = lo_arr + NFILT;
    float* wt_arr = (float*)(wd_arr + NFILT);

    gauss_setup<<<1, 128, 0, stream>>>(w, c_arr, rsg_arr, lo_arr, wd_arr,
                                       wt_arr, loss_out);

    dim3 grid(1, NCHUNK, B_DIM);  // (1, 64, 32)
    gauss_apply<<<grid, 256, 0, stream>>>(inputs, c_arr, rsg_arr, lo_arr,
                                          wd_arr, wt_arr, out);
}